// Round 1
// baseline (307.459 us; speedup 1.0000x reference)
//
#include <hip/hip_runtime.h>

// B=8, N=4096, Din=128, Dout=256. TT=16 tokens/block -> M = 3*16 = 48 rows.
// bf16 2-way split (hi/mid) + 3 product-class MFMAs = ~24-bit GEMMs (validated:
// absmax 0.5 vs threshold 2.42; bf16-only fails at 22.4 via |x|/|d| noise
// amplification in the VN-LeakyReLU projection).
// R5: split f across 8 waves (512-thr blocks, nt=2): acc 96->48 regs.
// R6 (this round): occupancy was STILL register-bound — acc1 (24 regs) stayed
// live through GEMM2 for the epilogue's x, so 24(acc1)+24(acc2)+~48 arch ≈ 96
// unified regs -> only 2 blocks/CU (measured 43% occ). Fix:
//  (a) epilogue re-reads x from the Yt LDS stash (x̂ = h+m, err ~2^-16·|x|,
//      negligible vs absmax 0.5) -> acc1 dead after the stash;
//  (b) __launch_bounds__(512,6) caps unified regs at ~85 -> 3 blocks/CU
//      (LDS 3x50688 = 152KB <= 160KB);
//  (c) full unroll of both GEMM K-loops + manual ks=0 B-tile prefetch issued
//      BEFORE the preceding barrier, so L2 latency overlaps the barrier wait.
#define TT 16
#define NBLK 2048
#define LDA 136   // aT row stride (bf16): 128 + 8 pad, 16B-aligned rows
#define LDY 264   // Yt row stride (bf16): 256 + 8 pad, 16B-aligned rows

typedef short s16x8 __attribute__((ext_vector_type(8)));
typedef float f32x4 __attribute__((ext_vector_type(4)));

__device__ __forceinline__ unsigned short f2bf(float f) {
  union { float f; unsigned u; } v; v.f = f;
  unsigned r = v.u + 0x7FFFu + ((v.u >> 16) & 1u);   // RNE; inputs finite
  return (unsigned short)(r >> 16);
}
__device__ __forceinline__ float bf2f(unsigned short h) {
  union { unsigned u; float f; } v; v.u = ((unsigned)h) << 16;
  return v.f;
}
__device__ __forceinline__ void split2(float x, unsigned short& h, unsigned short& m) {
  h = f2bf(x);
  m = f2bf(x - bf2f(h));   // exact subtraction
}

__global__ __launch_bounds__(256) void prep_kernel(
    const float* __restrict__ A, const float* __restrict__ Bm,
    const float* __restrict__ C, const float* __restrict__ W,
    unsigned short* __restrict__ M3h, unsigned short* __restrict__ M3m,
    unsigned short* __restrict__ Wh, unsigned short* __restrict__ Wm) {
  int tid = blockIdx.x * 256 + threadIdx.x;
  if (tid < 128 * 256) {
    unsigned short h, m;
    split2(A[tid] + Bm[tid] + C[tid], h, m);
    M3h[tid] = h; M3m[tid] = m;
  } else {
    int t2 = tid - 128 * 256;
    unsigned short h, m;
    split2(W[t2], h, m);
    Wh[t2] = h; Wm[t2] = m;
  }
}

__global__ __launch_bounds__(512, 6) void affine_vnrelu_mfma(
    const float* __restrict__ X, const float* __restrict__ J,
    const unsigned short* __restrict__ M3h, const unsigned short* __restrict__ M3m,
    const unsigned short* __restrict__ Wh, const unsigned short* __restrict__ Wm,
    float* __restrict__ out) {
  // union: phase A/B -> aT splits 2 x [48][LDA]; phase C/D -> Yt 2 x [48][LDY]
  __shared__ unsigned short smem[2 * 48 * LDY];   // 50688 B -> 3 blocks/CU
  unsigned short* aTh = smem;
  unsigned short* aTm = smem + 48 * LDA;

  const int tid = threadIdx.x;
  const int lane = tid & 63;
  const int w = tid >> 6;          // wave 0..7 -> f slice [32w, 32w+32)
  const int quad = lane >> 4;
  const int nl = lane & 15;
  const long g0 = (long)blockIdx.x * TT;
  const int b = (int)(g0 >> 12);   // N = 4096
  const int n0 = (int)(g0 & 4095);
  const int f0 = w * 32;

  // ---------------- Phase A: Gram-Schmidt + a = R^T X, split to bf16x2 ------
  #pragma unroll
  for (int k = 0; k < 4; ++k) {
    int p = k * 512 + tid;
    int t = p >> 7;
    int dch = p & 127;
    long base = (g0 + t) * 128 + dch;
    const float* Xp = X + base * 3;
    const float* Jp = J + base * 6;
    float x0 = Xp[0], x1 = Xp[1], x2 = Xp[2];
    float j0 = Jp[0], j1 = Jp[1], j2 = Jp[2], j3 = Jp[3], j4 = Jp[4], j5 = Jp[5];
    float c00 = j0, c01 = j2, c02 = j4;          // col0 of the 3x2
    float a20 = j1, a21 = j3, a22 = j5;          // col1
    float n1 = sqrtf(c00 * c00 + c01 * c01 + c02 * c02);
    float inv1 = 1.0f / fmaxf(n1, 1e-12f);
    float b10 = c00 * inv1, b11 = c01 * inv1, b12 = c02 * inv1;
    float pr = b10 * a20 + b11 * a21 + b12 * a22;
    float u0 = a20 - pr * b10, u1 = a21 - pr * b11, u2 = a22 - pr * b12;
    float n2 = sqrtf(u0 * u0 + u1 * u1 + u2 * u2);
    float inv2 = 1.0f / fmaxf(n2, 1e-12f);
    float b20 = u0 * inv2, b21 = u1 * inv2, b22 = u2 * inv2;
    float b30 = b11 * b22 - b12 * b21;
    float b31 = b12 * b20 - b10 * b22;
    float b32 = b10 * b21 - b11 * b20;
    unsigned short h, m;
    int r0 = t * LDA + dch;
    split2(b10 * x0 + b11 * x1 + b12 * x2, h, m); aTh[r0] = h; aTm[r0] = m;
    int r1 = (16 + t) * LDA + dch;
    split2(b20 * x0 + b21 * x1 + b22 * x2, h, m); aTh[r1] = h; aTm[r1] = m;
    int r2 = (32 + t) * LDA + dch;
    split2(b30 * x0 + b31 * x1 + b32 * x2, h, m); aTh[r2] = h; aTm[r2] = m;
  }

  // prefetch GEMM1 ks=0 B-tiles (global/L2, independent of LDS) so their
  // latency overlaps the barrier wait below
  s16x8 p1h[2], p1m[2];
  #pragma unroll
  for (int nt = 0; nt < 2; ++nt) {
    int bo = (f0 + nt * 16 + nl) * 128 + quad * 8;
    p1h[nt] = *(const s16x8*)(M3h + bo);
    p1m[nt] = *(const s16x8*)(M3m + bo);
  }
  __syncthreads();

  const f32x4 zz = {0.f, 0.f, 0.f, 0.f};

  // ---------------- GEMM1: Y[j][f] = sum_e aT[j][e] * M3[f][e] (split x3) ----
  f32x4 acc1[3][2];
  #pragma unroll
  for (int mt = 0; mt < 3; ++mt)
    #pragma unroll
    for (int nt = 0; nt < 2; ++nt) acc1[mt][nt] = zz;

  #pragma unroll
  for (int ks = 0; ks < 4; ++ks) {
    int e0 = ks * 32 + quad * 8;
    s16x8 bh[2], bm[2];
    if (ks == 0) {
      bh[0] = p1h[0]; bh[1] = p1h[1]; bm[0] = p1m[0]; bm[1] = p1m[1];
    } else {
      #pragma unroll
      for (int nt = 0; nt < 2; ++nt) {
        int bo = (f0 + nt * 16 + nl) * 128 + e0;
        bh[nt] = *(const s16x8*)(M3h + bo);
        bm[nt] = *(const s16x8*)(M3m + bo);
      }
    }
    #pragma unroll
    for (int mt = 0; mt < 3; ++mt) {
      int ao = (mt * 16 + nl) * LDA + e0;
      s16x8 ah = *(const s16x8*)(aTh + ao);
      s16x8 am = *(const s16x8*)(aTm + ao);
      #pragma unroll
      for (int nt = 0; nt < 2; ++nt) {
        f32x4 a = acc1[mt][nt];
        a = __builtin_amdgcn_mfma_f32_16x16x32_bf16(ah, bh[nt], a, 0, 0, 0);
        a = __builtin_amdgcn_mfma_f32_16x16x32_bf16(ah, bm[nt], a, 0, 0, 0);
        a = __builtin_amdgcn_mfma_f32_16x16x32_bf16(am, bh[nt], a, 0, 0, 0);
        acc1[mt][nt] = a;
      }
    }
  }

  // prefetch GEMM2 ks=0 W-tiles (global/L2) so their latency overlaps the
  // stash + two barriers below
  s16x8 p2h[2], p2m[2];
  #pragma unroll
  for (int nt = 0; nt < 2; ++nt) {
    int bo = (f0 + nt * 16 + nl) * 256 + quad * 8;
    p2h[nt] = *(const s16x8*)(Wh + bo);
    p2m[nt] = *(const s16x8*)(Wm + bo);
  }
  __syncthreads();   // aT region about to be overwritten by Yt

  // ---------------- stash Y as bf16x2 (exact split of fp32 acc) -------------
  // acc1 DIES here: the epilogue reconstructs x from this stash (h+m), so
  // only acc2 is live through GEMM2 -> ~24 fewer regs -> 3 blocks/CU.
  unsigned short* Yth = smem;
  unsigned short* Ytm = smem + 48 * LDY;
  #pragma unroll
  for (int mt = 0; mt < 3; ++mt)
    #pragma unroll
    for (int nt = 0; nt < 2; ++nt)
      #pragma unroll
      for (int r = 0; r < 4; ++r) {
        unsigned short h, m;
        split2(acc1[mt][nt][r], h, m);
        int yo = (mt * 16 + quad * 4 + r) * LDY + f0 + nt * 16 + nl;
        Yth[yo] = h; Ytm[yo] = m;
      }
  __syncthreads();

  // ---------------- GEMM2: d[j][o] = sum_c Yt[j][c] * W[o][c] (split x3) ----
  f32x4 acc2[3][2];
  #pragma unroll
  for (int mt = 0; mt < 3; ++mt)
    #pragma unroll
    for (int nt = 0; nt < 2; ++nt) acc2[mt][nt] = zz;

  #pragma unroll
  for (int ks = 0; ks < 8; ++ks) {
    int c0 = ks * 32 + quad * 8;
    s16x8 bh[2], bm[2];
    if (ks == 0) {
      bh[0] = p2h[0]; bh[1] = p2h[1]; bm[0] = p2m[0]; bm[1] = p2m[1];
    } else {
      #pragma unroll
      for (int nt = 0; nt < 2; ++nt) {
        int bo = (f0 + nt * 16 + nl) * 256 + c0;
        bh[nt] = *(const s16x8*)(Wh + bo);
        bm[nt] = *(const s16x8*)(Wm + bo);
      }
    }
    #pragma unroll
    for (int mt = 0; mt < 3; ++mt) {
      int ao = (mt * 16 + nl) * LDY + c0;
      s16x8 ah = *(const s16x8*)(Yth + ao);
      s16x8 am = *(const s16x8*)(Ytm + ao);
      #pragma unroll
      for (int nt = 0; nt < 2; ++nt) {
        f32x4 a = acc2[mt][nt];
        a = __builtin_amdgcn_mfma_f32_16x16x32_bf16(ah, bh[nt], a, 0, 0, 0);
        a = __builtin_amdgcn_mfma_f32_16x16x32_bf16(ah, bm[nt], a, 0, 0, 0);
        a = __builtin_amdgcn_mfma_f32_16x16x32_bf16(am, bh[nt], a, 0, 0, 0);
        acc2[mt][nt] = a;
      }
    }
  }

  // ---------------- VN-LeakyReLU (lane-local) + float4 stores ---------------
  // x is re-read from the Yt stash: x̂ = bf2f(h)+bf2f(m), |x̂-x| <= 2^-16·|x|
  // (negligible vs the bf16-split GEMM noise already in absmax 0.5).
  // d_i = acc2[i][nt][r] at f = f0 + nt*16 + nl, t = quad*4 + r.
  #pragma unroll
  for (int nt = 0; nt < 2; ++nt) {
    int f = f0 + nt * 16 + nl;
    float* ob = out + ((long)(b * 256 + f) * 3) * 4096 + n0 + quad * 4;
    float o[3][4];
    #pragma unroll
    for (int r = 0; r < 4; ++r) {
      int row = quad * 4 + r;
      float x0 = bf2f(Yth[row * LDY + f])        + bf2f(Ytm[row * LDY + f]);
      float x1 = bf2f(Yth[(16 + row) * LDY + f]) + bf2f(Ytm[(16 + row) * LDY + f]);
      float x2 = bf2f(Yth[(32 + row) * LDY + f]) + bf2f(Ytm[(32 + row) * LDY + f]);
      float d0 = acc2[0][nt][r], d1 = acc2[1][nt][r], d2 = acc2[2][nt][r];
      float dot = x0 * d0 + x1 * d1 + x2 * d2;
      float dn = d0 * d0 + d1 * d1 + d2 * d2;
      float s = (dot < 0.0f) ? (0.8f * dot / (dn + 1e-6f)) : 0.0f;
      o[0][r] = x0 - s * d0;
      o[1][r] = x1 - s * d1;
      o[2][r] = x2 - s * d2;
    }
    #pragma unroll
    for (int i = 0; i < 3; ++i)
      *(float4*)(ob + ((long)i * 4096)) = make_float4(o[i][0], o[i][1], o[i][2], o[i][3]);
  }
}

extern "C" void kernel_launch(void* const* d_in, const int* in_sizes, int n_in,
                              void* d_out, int out_size, void* d_ws, size_t ws_size,
                              hipStream_t stream) {
  const float* X = (const float*)d_in[0];   // [8,4096,128,3]
  const float* J = (const float*)d_in[1];   // [8,4096,128,3,2]
  const float* A = (const float*)d_in[2];   // [256,128]
  const float* B = (const float*)d_in[3];   // [256,128]
  const float* C = (const float*)d_in[4];   // [256,128]
  const float* W = (const float*)d_in[5];   // [256,256]
  unsigned short* M3h = (unsigned short*)d_ws;        // 2 x 32768 bf16
  unsigned short* M3m = M3h + 128 * 256;
  unsigned short* Wh  = M3m + 128 * 256;              // 2 x 65536 bf16
  unsigned short* Wm  = Wh + 256 * 256;               // total 384 KB of ws
  float* out = (float*)d_out;               // [8,256,3,4096]

  prep_kernel<<<(128 * 256 + 256 * 256) / 256, 256, 0, stream>>>(
      A, B, C, W, M3h, M3m, Wh, Wm);
  affine_vnrelu_mfma<<<NBLK, 512, 0, stream>>>(
      X, J, M3h, M3m, Wh, Wm, out);
}